// Round 1
// baseline (891.372 us; speedup 1.0000x reference)
//
#include <hip/hip_runtime.h>
#include <cstdint>
#include <cstddef>

typedef _Float16 half8 __attribute__((ext_vector_type(8)));
typedef _Float16 half4_t __attribute__((ext_vector_type(4)));
typedef float f32x4 __attribute__((ext_vector_type(4)));

#define LOG2E 1.4426950408889634f

// async global->LDS, 16B per lane. LDS dest must be wave-uniform base + lane*16.
__device__ __forceinline__ void async16(const void* g, void* l) {
  __builtin_amdgcn_global_load_lds((const __attribute__((address_space(1))) void*)g,
                                   (__attribute__((address_space(3))) void*)l,
                                   16, 0, 0);
}

// ---------------- fp32 -> fp16 convert ----------------
__global__ __launch_bounds__(256) void cvt_f32_f16(const float* __restrict__ in,
                                                   _Float16* __restrict__ out, int n) {
  int i = (blockIdx.x * 256 + threadIdx.x) * 8;
  if (i + 7 < n) {
    f32x4 a = *(const f32x4*)(in + i);
    f32x4 b = *(const f32x4*)(in + i + 4);
    half8 h;
    h[0] = (_Float16)a[0]; h[1] = (_Float16)a[1];
    h[2] = (_Float16)a[2]; h[3] = (_Float16)a[3];
    h[4] = (_Float16)b[0]; h[5] = (_Float16)b[1];
    h[6] = (_Float16)b[2]; h[7] = (_Float16)b[3];
    *(half8*)(out + i) = h;
  }
}

// ---------------- shared 128x128x1024 NT-GEMM mainloop ----------------
// C[m,n] = sum_k A[m,k] * W[n,k]; both row-major with K=1024.
// m97 structure: BK=32, global_load_lds width16, 16x16x32 f16 MFMA, 4 waves 2x2.
__device__ __forceinline__ void gemm128_mainloop(const _Float16* __restrict__ Ap,
                                                 const _Float16* __restrict__ Wp,
                                                 _Float16* As, _Float16* Bs,
                                                 f32x4 (&acc)[4][4]) {
  const int tid = threadIdx.x;
  const int lane = tid & 63;
  const int wid = tid >> 6;
  const int c = lane & 15, quad = lane >> 4;
  const int wm0 = (wid >> 1) * 64, wn0 = (wid & 1) * 64;
  const _Float16* ga0 = Ap + (size_t)(tid >> 2) * 1024 + (tid & 3) * 8;
  const _Float16* ga1 = ga0 + (size_t)64 * 1024;
  const _Float16* gb0 = Wp + (size_t)(tid >> 2) * 1024 + (tid & 3) * 8;
  const _Float16* gb1 = gb0 + (size_t)64 * 1024;
  _Float16* la0 = &As[tid * 8];
  _Float16* la1 = &As[(tid + 256) * 8];
  _Float16* lb0 = &Bs[tid * 8];
  _Float16* lb1 = &Bs[(tid + 256) * 8];
  for (int k0 = 0; k0 < 1024; k0 += 32) {
    __syncthreads();
    async16(ga0 + k0, la0);
    async16(ga1 + k0, la1);
    async16(gb0 + k0, lb0);
    async16(gb1 + k0, lb1);
    __syncthreads();  // drains vmcnt -> staged data visible
    half8 af[4], bf[4];
#pragma unroll
    for (int i = 0; i < 4; ++i)
      af[i] = *(const half8*)&As[(wm0 + i * 16 + c) * 32 + quad * 8];
#pragma unroll
    for (int j = 0; j < 4; ++j)
      bf[j] = *(const half8*)&Bs[(wn0 + j * 16 + c) * 32 + quad * 8];
#pragma unroll
    for (int i = 0; i < 4; ++i)
#pragma unroll
      for (int j = 0; j < 4; ++j)
        acc[i][j] = __builtin_amdgcn_mfma_f32_16x16x32_f16(af[i], bf[j], acc[i][j], 0, 0, 0);
  }
}

// ---------------- QKV projection, epilogue scatters to (B,H,T,64) f16 ----------------
__global__ __launch_bounds__(256, 2) void gemm_qkv(
    const _Float16* __restrict__ A,
    const _Float16* __restrict__ Wq, const _Float16* __restrict__ Wk,
    const _Float16* __restrict__ Wv,
    const float* __restrict__ Bq, const float* __restrict__ Bk,
    const float* __restrict__ Bv,
    _Float16* __restrict__ Qo, _Float16* __restrict__ Ko, _Float16* __restrict__ Vo) {
  __shared__ __align__(16) _Float16 As[128 * 32];
  __shared__ __align__(16) _Float16 Bs[128 * 32];
  const int z = blockIdx.z;
  const _Float16* W = (z == 0) ? Wq : (z == 1) ? Wk : Wv;
  const float* bias = (z == 0) ? Bq : (z == 1) ? Bk : Bv;
  _Float16* out = (z == 0) ? Qo : (z == 1) ? Ko : Vo;
  const float scale = (z == 0) ? LOG2E : 1.0f;  // fold exp->exp2 conversion into Q
  const int m0 = blockIdx.x * 128, n0 = blockIdx.y * 128;
  f32x4 acc[4][4] = {};
  gemm128_mainloop(A + (size_t)m0 * 1024, W + (size_t)n0 * 1024, As, Bs, acc);
  const int tid = threadIdx.x;
  const int lane = tid & 63, wid = tid >> 6;
  const int c = lane & 15, quad = lane >> 4;
  const int wm0 = (wid >> 1) * 64, wn0 = (wid & 1) * 64;
#pragma unroll
  for (int j = 0; j < 4; ++j) {
    int n = n0 + wn0 + j * 16 + c;
    float bv = bias[n];
    int h = n >> 6, d = n & 63;
#pragma unroll
    for (int i = 0; i < 4; ++i) {
      int mb = m0 + wm0 + i * 16 + quad * 4;
#pragma unroll
      for (int r = 0; r < 4; ++r) {
        int m = mb + r;
        float v = (acc[i][j][r] + bv) * scale;
        int bb = m >> 12, t = m & 4095;
        out[(((size_t)(bb * 16 + h) * 4096 + t) << 6) + d] = (_Float16)v;
      }
    }
  }
}

// ---------------- out projection, fp32 epilogue ----------------
__global__ __launch_bounds__(256, 2) void gemm_out(
    const _Float16* __restrict__ A, const _Float16* __restrict__ W,
    const float* __restrict__ bias, float* __restrict__ out) {
  __shared__ __align__(16) _Float16 As[128 * 32];
  __shared__ __align__(16) _Float16 Bs[128 * 32];
  const int m0 = blockIdx.x * 128, n0 = blockIdx.y * 128;
  f32x4 acc[4][4] = {};
  gemm128_mainloop(A + (size_t)m0 * 1024, W + (size_t)n0 * 1024, As, Bs, acc);
  const int tid = threadIdx.x;
  const int lane = tid & 63, wid = tid >> 6;
  const int c = lane & 15, quad = lane >> 4;
  const int wm0 = (wid >> 1) * 64, wn0 = (wid & 1) * 64;
#pragma unroll
  for (int j = 0; j < 4; ++j) {
    int n = n0 + wn0 + j * 16 + c;
    float bv = bias[n];
#pragma unroll
    for (int i = 0; i < 4; ++i) {
      int mb = m0 + wm0 + i * 16 + quad * 4;
#pragma unroll
      for (int r = 0; r < 4; ++r) {
        int m = mb + r;
        out[(size_t)m * 1024 + n] = acc[i][j][r] + bv;
      }
    }
  }
}

// ---------------- V transpose: (B,H,T,64) -> (B,H,64,T) ----------------
__global__ __launch_bounds__(256) void transpose_v(const _Float16* __restrict__ in,
                                                   _Float16* __restrict__ out) {
  size_t gid = (size_t)blockIdx.x * 256 + threadIdx.x;
  int tc = (int)(gid & 511);          // t-chunk of 8
  int d = (int)((gid >> 9) & 63);
  int bh = (int)(gid >> 15);
  const _Float16* src = in + ((size_t)bh << 18);
  half8 v;
#pragma unroll
  for (int jj = 0; jj < 8; ++jj) v[jj] = src[(size_t)(tc * 8 + jj) * 64 + d];
  *(half8*)&out[(((size_t)bh * 64 + d) << 12) + tc * 8] = v;  // coalesced 16B stores
}

// ---------------- fused flash attention (buggy-variant-faithful) ----------------
// Q pre-scaled by log2(e); S^T = K*Q^T via MFMA so P lands key-consecutive in
// each lane -> b64 P writes to padded LDS; PV reads P as A-operand (b128).
// O accumulator is deliberately NOT rescaled (matches reference); L is.
__global__ __launch_bounds__(256, 2) void fa_kernel(
    const _Float16* __restrict__ Qg, const _Float16* __restrict__ Kg,
    const _Float16* __restrict__ VgT, _Float16* __restrict__ Og) {
  __shared__ __align__(16) _Float16 Ks[128 * 64];      // (key, d), chunk-swizzled
  __shared__ __align__(16) _Float16 VsT[64 * 128];     // (d, key), chunk-swizzled
  __shared__ __align__(16) _Float16 PsQ[128 * 136];    // union: Q staging / P (stride 136)

  const int tid = threadIdx.x;
  const int lane = tid & 63, wid = tid >> 6;
  const int c = lane & 15, quad = lane >> 4;
  const int bh = blockIdx.x, qt = blockIdx.y;  // bh fast -> head pinned to one XCD
  const int b = bh >> 4, h = bh & 15;
  const size_t hoff = (size_t)bh * 4096 * 64;
  const _Float16* Qh = Qg + hoff + (size_t)qt * 128 * 64;
  const _Float16* Kh = Kg + hoff;
  const _Float16* Vh = VgT + hoff;  // (64, 4096)

  // stage Q tile (128x64) with per-row chunk swizzle ck ^= row&7
#pragma unroll
  for (int it = 0; it < 4; ++it) {
    int cidx = it * 256 + tid;
    int row = cidx >> 3, ck = (cidx & 7) ^ (row & 7);
    async16(Qh + row * 64 + ck * 8, &PsQ[cidx * 8]);
  }
  __syncthreads();

  const int wq0 = wid * 32;  // this wave's 32 queries
  half8 qf[2][2];            // hoisted Q fragments [qtile][khalf]
#pragma unroll
  for (int i = 0; i < 2; ++i)
#pragma unroll
    for (int kk = 0; kk < 2; ++kk) {
      int row = wq0 + i * 16 + c;
      int ck = (kk * 4 + quad) ^ (row & 7);
      qf[i][kk] = *(const half8*)&PsQ[row * 64 + ck * 8];
    }

  f32x4 oacc[2][4] = {};
  float M[2] = {-__builtin_inff(), -__builtin_inff()};
  float L[2] = {0.f, 0.f};

  for (int j = 0; j < 32; ++j) {
    __syncthreads();  // prior compute done (also fences Q-frag reads on j==0)
#pragma unroll
    for (int it = 0; it < 4; ++it) {
      int cidx = it * 256 + tid;
      int row = cidx >> 3, ck = (cidx & 7) ^ (row & 7);
      async16(Kh + (size_t)(j * 128 + row) * 64 + ck * 8, &Ks[cidx * 8]);
    }
#pragma unroll
    for (int it = 0; it < 4; ++it) {
      int cidx = it * 256 + tid;
      int d = cidx >> 4, ck = (cidx & 15) ^ (d & 7);
      async16(Vh + (size_t)d * 4096 + j * 128 + ck * 8, &VsT[cidx * 8]);
    }
    __syncthreads();

    // S^T[key][query] = K * Q^T ; sacc[keytile][qtile]
    f32x4 sacc[8][2];
#pragma unroll
    for (int j8 = 0; j8 < 8; ++j8) {
      int krow = j8 * 16 + c;
      int ck = quad ^ (krow & 7);
      half8 kf = *(const half8*)&Ks[krow * 64 + ck * 8];
      f32x4 z = {};
      sacc[j8][0] = __builtin_amdgcn_mfma_f32_16x16x32_f16(kf, qf[0][0], z, 0, 0, 0);
      sacc[j8][1] = __builtin_amdgcn_mfma_f32_16x16x32_f16(kf, qf[1][0], z, 0, 0, 0);
    }
#pragma unroll
    for (int j8 = 0; j8 < 8; ++j8) {
      int krow = j8 * 16 + c;
      int ck = (4 + quad) ^ (krow & 7);
      half8 kf = *(const half8*)&Ks[krow * 64 + ck * 8];
      sacc[j8][0] = __builtin_amdgcn_mfma_f32_16x16x32_f16(kf, qf[0][1], sacc[j8][0], 0, 0, 0);
      sacc[j8][1] = __builtin_amdgcn_mfma_f32_16x16x32_f16(kf, qf[1][1], sacc[j8][1], 0, 0, 0);
    }

    // online stats: query = wq0 + i*16 + c (lane column); keys live in (j8, quad, r)
#pragma unroll
    for (int i = 0; i < 2; ++i) {
      float mx = sacc[0][i][0];
#pragma unroll
      for (int j8 = 0; j8 < 8; ++j8)
#pragma unroll
        for (int r = 0; r < 4; ++r) mx = fmaxf(mx, sacc[j8][i][r]);
      mx = fmaxf(mx, __shfl_xor(mx, 16));
      mx = fmaxf(mx, __shfl_xor(mx, 32));
      float Mn = fmaxf(M[i], mx);
      float al = exp2f(M[i] - Mn);
      M[i] = Mn;
      float rs = 0.f;
#pragma unroll
      for (int j8 = 0; j8 < 8; ++j8) {
        f32x4 p;
#pragma unroll
        for (int r = 0; r < 4; ++r) {
          p[r] = exp2f(sacc[j8][i][r] - Mn);
          rs += p[r];
        }
        half4_t ph;
        ph[0] = (_Float16)p[0]; ph[1] = (_Float16)p[1];
        ph[2] = (_Float16)p[2]; ph[3] = (_Float16)p[3];
        // P row-major, stride 136 (272B: 16B-aligned rows, conflict-free b64 writes)
        *(half4_t*)&PsQ[(wq0 + i * 16 + c) * 136 + j8 * 16 + quad * 4] = ph;
      }
      rs += __shfl_xor(rs, 16);
      rs += __shfl_xor(rs, 32);
      L[i] = al * L[i] + rs;  // L IS rescaled; O is NOT (faithful to reference)
    }

    // PV: O[q][d] += P[q][k] * V[k][d]   (P rows are this wave's own -> in-order DS, no barrier)
#pragma unroll
    for (int ks = 0; ks < 4; ++ks) {
      half8 pf0 = *(const half8*)&PsQ[(wq0 + c) * 136 + ks * 32 + quad * 8];
      half8 pf1 = *(const half8*)&PsQ[(wq0 + 16 + c) * 136 + ks * 32 + quad * 8];
#pragma unroll
      for (int n = 0; n < 4; ++n) {
        int d = n * 16 + c;
        int ck = (ks * 4 + quad) ^ (d & 7);
        half8 vf = *(const half8*)&VsT[d * 128 + ck * 8];
        oacc[0][n] = __builtin_amdgcn_mfma_f32_16x16x32_f16(pf0, vf, oacc[0][n], 0, 0, 0);
        oacc[1][n] = __builtin_amdgcn_mfma_f32_16x16x32_f16(pf1, vf, oacc[1][n], 0, 0, 0);
      }
    }
  }

  // epilogue: O/L, store f16 to (B,T,1024)
#pragma unroll
  for (int i = 0; i < 2; ++i) {
#pragma unroll
    for (int r = 0; r < 4; ++r) {
      float Lq = __shfl(L[i], quad * 4 + r);  // lanes 0..15 hold queries 0..15 of this tile
      float inv = 1.0f / Lq;
      int t = qt * 128 + wq0 + i * 16 + quad * 4 + r;
      size_t base = (((size_t)(b * 4096 + t)) << 10) + h * 64;
#pragma unroll
      for (int n = 0; n < 4; ++n)
        Og[base + n * 16 + c] = (_Float16)(oacc[i][n][r] * inv);
    }
  }
}

// ---------------- launcher ----------------
extern "C" void kernel_launch(void* const* d_in, const int* in_sizes, int n_in,
                              void* d_out, int out_size, void* d_ws, size_t ws_size,
                              hipStream_t stream) {
  const float* x = (const float*)d_in[0];
  const float* wq = (const float*)d_in[1];
  const float* bq = (const float*)d_in[2];
  const float* wk = (const float*)d_in[3];
  const float* bk = (const float*)d_in[4];
  const float* wv = (const float*)d_in[5];
  const float* bv = (const float*)d_in[6];
  const float* wo = (const float*)d_in[7];
  const float* bo = (const float*)d_in[8];

  char* ws = (char*)d_ws;
  const size_t MB = 1024 * 1024;
  _Float16* xb = (_Float16*)(ws);               // 32MB; reused as VgT after QKV
  _Float16* wq16 = (_Float16*)(ws + 32 * MB);   // 2MB each
  _Float16* wk16 = (_Float16*)(ws + 34 * MB);
  _Float16* wv16 = (_Float16*)(ws + 36 * MB);
  _Float16* wo16 = (_Float16*)(ws + 38 * MB);
  _Float16* Qg = (_Float16*)(ws + 40 * MB);     // (B,H,T,64) f16, 32MB
  _Float16* Kg = (_Float16*)(ws + 72 * MB);     // 32MB
  _Float16* Vg = (_Float16*)(ws + 104 * MB);    // 32MB; reused as Oatt after transpose
  _Float16* VgT = xb;                           // (B,H,64,T)
  _Float16* Oatt = Vg;                          // (B,T,1024)

  cvt_f32_f16<<<8192, 256, 0, stream>>>(x, xb, 16777216);
  cvt_f32_f16<<<512, 256, 0, stream>>>(wq, wq16, 1048576);
  cvt_f32_f16<<<512, 256, 0, stream>>>(wk, wk16, 1048576);
  cvt_f32_f16<<<512, 256, 0, stream>>>(wv, wv16, 1048576);
  cvt_f32_f16<<<512, 256, 0, stream>>>(wo, wo16, 1048576);

  gemm_qkv<<<dim3(128, 8, 3), 256, 0, stream>>>(xb, wq16, wk16, wv16,
                                                bq, bk, bv, Qg, Kg, Vg);
  transpose_v<<<8192, 256, 0, stream>>>(Vg, VgT);
  fa_kernel<<<dim3(64, 32), 256, 0, stream>>>(Qg, Kg, VgT, Oatt);
  gemm_out<<<dim3(128, 8), 256, 0, stream>>>(Oatt, wo16, bo, (float*)d_out);
}

// Round 3
// 883.331 us; speedup vs baseline: 1.0091x; 1.0091x over previous
//
#include <hip/hip_runtime.h>
#include <cstdint>
#include <cstddef>

typedef _Float16 half8 __attribute__((ext_vector_type(8)));
typedef _Float16 half4_t __attribute__((ext_vector_type(4)));
typedef _Float16 half2_t __attribute__((ext_vector_type(2)));
typedef float f32x4 __attribute__((ext_vector_type(4)));

#define LOG2E 1.4426950408889634f

// async global->LDS, 16B per lane. LDS dest must be wave-uniform base + lane*16.
__device__ __forceinline__ void async16(const void* g, void* l) {
  __builtin_amdgcn_global_load_lds((const __attribute__((address_space(1))) void*)g,
                                   (__attribute__((address_space(3))) void*)l,
                                   16, 0, 0);
}

__device__ __forceinline__ f32x4 vmax4(f32x4 a, f32x4 b) {
  f32x4 r;
  r[0] = fmaxf(a[0], b[0]); r[1] = fmaxf(a[1], b[1]);
  r[2] = fmaxf(a[2], b[2]); r[3] = fmaxf(a[3], b[3]);
  return r;
}

__device__ __forceinline__ half2_t pk_cvt(float a, float b) {
  return __builtin_bit_cast(half2_t, __builtin_amdgcn_cvt_pkrtz(a, b));
}

// ---------------- fp32 -> fp16 convert ----------------
__global__ __launch_bounds__(256) void cvt_f32_f16(const float* __restrict__ in,
                                                   _Float16* __restrict__ out, int n) {
  int i = (blockIdx.x * 256 + threadIdx.x) * 8;
  if (i + 7 < n) {
    f32x4 a = *(const f32x4*)(in + i);
    f32x4 b = *(const f32x4*)(in + i + 4);
    half8 h;
    h[0] = (_Float16)a[0]; h[1] = (_Float16)a[1];
    h[2] = (_Float16)a[2]; h[3] = (_Float16)a[3];
    h[4] = (_Float16)b[0]; h[5] = (_Float16)b[1];
    h[6] = (_Float16)b[2]; h[7] = (_Float16)b[3];
    *(half8*)(out + i) = h;
  }
}

// 4 weight matrices (1M elems each) in one launch
__global__ __launch_bounds__(256) void cvt_w4(
    const float* __restrict__ a, const float* __restrict__ b,
    const float* __restrict__ c, const float* __restrict__ d,
    _Float16* __restrict__ oa, _Float16* __restrict__ ob,
    _Float16* __restrict__ oc, _Float16* __restrict__ od) {
  int seg = blockIdx.x >> 9;
  const float* src = (seg == 0) ? a : (seg == 1) ? b : (seg == 2) ? c : d;
  _Float16* dst = (seg == 0) ? oa : (seg == 1) ? ob : (seg == 2) ? oc : od;
  int i = ((blockIdx.x & 511) * 256 + threadIdx.x) * 8;
  f32x4 x0 = *(const f32x4*)(src + i);
  f32x4 x1 = *(const f32x4*)(src + i + 4);
  half8 h;
  h[0] = (_Float16)x0[0]; h[1] = (_Float16)x0[1];
  h[2] = (_Float16)x0[2]; h[3] = (_Float16)x0[3];
  h[4] = (_Float16)x1[0]; h[5] = (_Float16)x1[1];
  h[6] = (_Float16)x1[2]; h[7] = (_Float16)x1[3];
  *(half8*)(dst + i) = h;
}

// ---------------- shared 128x128x1024 NT-GEMM mainloop ----------------
__device__ __forceinline__ void gemm128_mainloop(const _Float16* __restrict__ Ap,
                                                 const _Float16* __restrict__ Wp,
                                                 _Float16* As, _Float16* Bs,
                                                 f32x4 (&acc)[4][4]) {
  const int tid = threadIdx.x;
  const int lane = tid & 63;
  const int wid = tid >> 6;
  const int c = lane & 15, quad = lane >> 4;
  const int wm0 = (wid >> 1) * 64, wn0 = (wid & 1) * 64;
  const _Float16* ga0 = Ap + (size_t)(tid >> 2) * 1024 + (tid & 3) * 8;
  const _Float16* ga1 = ga0 + (size_t)64 * 1024;
  const _Float16* gb0 = Wp + (size_t)(tid >> 2) * 1024 + (tid & 3) * 8;
  const _Float16* gb1 = gb0 + (size_t)64 * 1024;
  _Float16* la0 = &As[tid * 8];
  _Float16* la1 = &As[(tid + 256) * 8];
  _Float16* lb0 = &Bs[tid * 8];
  _Float16* lb1 = &Bs[(tid + 256) * 8];
  for (int k0 = 0; k0 < 1024; k0 += 32) {
    __syncthreads();
    async16(ga0 + k0, la0);
    async16(ga1 + k0, la1);
    async16(gb0 + k0, lb0);
    async16(gb1 + k0, lb1);
    __syncthreads();
    half8 af[4], bf[4];
#pragma unroll
    for (int i = 0; i < 4; ++i)
      af[i] = *(const half8*)&As[(wm0 + i * 16 + c) * 32 + quad * 8];
#pragma unroll
    for (int j = 0; j < 4; ++j)
      bf[j] = *(const half8*)&Bs[(wn0 + j * 16 + c) * 32 + quad * 8];
#pragma unroll
    for (int i = 0; i < 4; ++i)
#pragma unroll
      for (int j = 0; j < 4; ++j)
        acc[i][j] = __builtin_amdgcn_mfma_f32_16x16x32_f16(af[i], bf[j], acc[i][j], 0, 0, 0);
  }
}

// ---------------- QKV projection ----------------
// z=0/1: scatter to (B,H,T,64); z=2: V stored directly TRANSPOSED (B,H,64,T).
__global__ __launch_bounds__(256, 2) void gemm_qkv(
    const _Float16* __restrict__ A,
    const _Float16* __restrict__ Wq, const _Float16* __restrict__ Wk,
    const _Float16* __restrict__ Wv,
    const float* __restrict__ Bq, const float* __restrict__ Bk,
    const float* __restrict__ Bv,
    _Float16* __restrict__ Qo, _Float16* __restrict__ Ko, _Float16* __restrict__ VoT) {
  __shared__ __align__(16) _Float16 As[128 * 32];
  __shared__ __align__(16) _Float16 Bs[128 * 32];
  const int z = blockIdx.z;
  const _Float16* W = (z == 0) ? Wq : (z == 1) ? Wk : Wv;
  const float* bias = (z == 0) ? Bq : (z == 1) ? Bk : Bv;
  const float scale = (z == 0) ? LOG2E : 1.0f;  // fold exp->exp2 into Q
  const int m0 = blockIdx.x * 128, n0 = blockIdx.y * 128;
  f32x4 acc[4][4] = {};
  gemm128_mainloop(A + (size_t)m0 * 1024, W + (size_t)n0 * 1024, As, Bs, acc);
  const int tid = threadIdx.x;
  const int lane = tid & 63, wid = tid >> 6;
  const int c = lane & 15, quad = lane >> 4;
  const int wm0 = (wid >> 1) * 64, wn0 = (wid & 1) * 64;
  if (z == 2) {
#pragma unroll
    for (int j = 0; j < 4; ++j) {
      int n = n0 + wn0 + j * 16 + c;
      float bvv = bias[n];
      int h = n >> 6, d = n & 63;
#pragma unroll
      for (int i = 0; i < 4; ++i) {
        int mb = m0 + wm0 + i * 16 + quad * 4;
        int bb = mb >> 12, t = mb & 4095;
        half4_t hv;
#pragma unroll
        for (int r = 0; r < 4; ++r) hv[r] = (_Float16)(acc[i][j][r] + bvv);
        *(half4_t*)&VoT[(((size_t)((bb * 16 + h) * 64 + d)) << 12) + t] = hv;
      }
    }
  } else {
    _Float16* out = (z == 0) ? Qo : Ko;
#pragma unroll
    for (int j = 0; j < 4; ++j) {
      int n = n0 + wn0 + j * 16 + c;
      float bvv = bias[n];
      int h = n >> 6, d = n & 63;
#pragma unroll
      for (int i = 0; i < 4; ++i) {
        int mb = m0 + wm0 + i * 16 + quad * 4;
#pragma unroll
        for (int r = 0; r < 4; ++r) {
          int m = mb + r;
          float v = (acc[i][j][r] + bvv) * scale;
          int bb = m >> 12, t = m & 4095;
          out[(((size_t)(bb * 16 + h) * 4096 + t) << 6) + d] = (_Float16)v;
        }
      }
    }
  }
}

// ---------------- out projection, fp32 epilogue ----------------
__global__ __launch_bounds__(256, 2) void gemm_out(
    const _Float16* __restrict__ A, const _Float16* __restrict__ W,
    const float* __restrict__ bias, float* __restrict__ out) {
  __shared__ __align__(16) _Float16 As[128 * 32];
  __shared__ __align__(16) _Float16 Bs[128 * 32];
  const int m0 = blockIdx.x * 128, n0 = blockIdx.y * 128;
  f32x4 acc[4][4] = {};
  gemm128_mainloop(A + (size_t)m0 * 1024, W + (size_t)n0 * 1024, As, Bs, acc);
  const int tid = threadIdx.x;
  const int lane = tid & 63, wid = tid >> 6;
  const int c = lane & 15, quad = lane >> 4;
  const int wm0 = (wid >> 1) * 64, wn0 = (wid & 1) * 64;
#pragma unroll
  for (int j = 0; j < 4; ++j) {
    int n = n0 + wn0 + j * 16 + c;
    float bv = bias[n];
#pragma unroll
    for (int i = 0; i < 4; ++i) {
      int mb = m0 + wm0 + i * 16 + quad * 4;
#pragma unroll
      for (int r = 0; r < 4; ++r) {
        int m = mb + r;
        out[(size_t)m * 1024 + n] = acc[i][j][r] + bv;
      }
    }
  }
}

// ---------------- fused flash attention (buggy-variant-faithful) ----------------
// LDS 52K -> 3 blocks/CU. Q staged through Ks. P buffer is per-wave private,
// 2-chunk skewed (write chunk ks while PV consumes ks-1), row stride 40 halves
// (20 words -> conflict-free b64 writes / b128 reads).
__global__ __launch_bounds__(256, 3) void fa_kernel(
    const _Float16* __restrict__ Qg, const _Float16* __restrict__ Kg,
    const _Float16* __restrict__ VgT, _Float16* __restrict__ Og) {
  __shared__ __align__(16) _Float16 Ks[128 * 64];    // Q staging, then K (key, d), swizzled
  __shared__ __align__(16) _Float16 VsT[64 * 128];   // (d, key), swizzled
  __shared__ __align__(16) _Float16 Pc[4][2][32 * 40];  // [wave][chunk][32 rows x 40]

  const int tid = threadIdx.x;
  const int lane = tid & 63, wid = tid >> 6;
  const int c = lane & 15, quad = lane >> 4;
  const int bh = blockIdx.x, qt = blockIdx.y;
  const int b = bh >> 4, h = bh & 15;
  const size_t hoff = (size_t)bh * 4096 * 64;
  const _Float16* Qh = Qg + hoff + (size_t)qt * 128 * 64;
  const _Float16* Kh = Kg + hoff;
  const _Float16* Vh = VgT + hoff;  // (64, 4096)

  // stage Q tile (128x64) into Ks, per-row chunk swizzle
#pragma unroll
  for (int it = 0; it < 4; ++it) {
    int cidx = it * 256 + tid;
    int row = cidx >> 3, ck = (cidx & 7) ^ (row & 7);
    async16(Qh + row * 64 + ck * 8, &Ks[cidx * 8]);
  }
  __syncthreads();

  const int wq0 = wid * 32;
  half8 qf[2][2];
#pragma unroll
  for (int i = 0; i < 2; ++i)
#pragma unroll
    for (int kk = 0; kk < 2; ++kk) {
      int row = wq0 + i * 16 + c;
      int ck = (kk * 4 + quad) ^ (c & 7);
      qf[i][kk] = *(const half8*)&Ks[row * 64 + ck * 8];
    }

  _Float16* Pw = &Pc[wid][0][0];  // two 1280-half chunks, contiguous
  f32x4 oacc[2][4] = {};
  float M[2] = {-__builtin_inff(), -__builtin_inff()};
  float L[2] = {0.f, 0.f};

  for (int j = 0; j < 32; ++j) {
    __syncthreads();  // prior iter's Ks/VsT reads done (and Q-frag reads on j==0)
#pragma unroll
    for (int it = 0; it < 4; ++it) {
      int cidx = it * 256 + tid;
      int row = cidx >> 3, ck = (cidx & 7) ^ (row & 7);
      async16(Kh + (size_t)(j * 128 + row) * 64 + ck * 8, &Ks[cidx * 8]);
    }
#pragma unroll
    for (int it = 0; it < 4; ++it) {
      int cidx = it * 256 + tid;
      int d = cidx >> 4, ck = (cidx & 15) ^ (d & 7);
      async16(Vh + (size_t)d * 4096 + j * 128 + ck * 8, &VsT[cidx * 8]);
    }
    __syncthreads();

    // S^T = K * Q^T for both q-tiles; sacc held in regs until exp phase
    f32x4 s0[8], s1[8];
#pragma unroll
    for (int j8 = 0; j8 < 8; ++j8) {
      int krow = j8 * 16 + c;
      int ck = quad ^ (c & 7);
      half8 kf = *(const half8*)&Ks[krow * 64 + ck * 8];
      f32x4 z = {};
      s0[j8] = __builtin_amdgcn_mfma_f32_16x16x32_f16(kf, qf[0][0], z, 0, 0, 0);
      s1[j8] = __builtin_amdgcn_mfma_f32_16x16x32_f16(kf, qf[1][0], z, 0, 0, 0);
    }
#pragma unroll
    for (int j8 = 0; j8 < 8; ++j8) {
      int krow = j8 * 16 + c;
      int ck = (4 + quad) ^ (c & 7);
      half8 kf = *(const half8*)&Ks[krow * 64 + ck * 8];
      s0[j8] = __builtin_amdgcn_mfma_f32_16x16x32_f16(kf, qf[0][1], s0[j8], 0, 0, 0);
      s1[j8] = __builtin_amdgcn_mfma_f32_16x16x32_f16(kf, qf[1][1], s1[j8], 0, 0, 0);
    }

    // running max per q-tile (tree + cross-quad)
    float Mn[2], al[2];
#pragma unroll
    for (int i = 0; i < 2; ++i) {
      f32x4* s = i ? s1 : s0;
      f32x4 m01 = vmax4(vmax4(s[0], s[1]), vmax4(s[2], s[3]));
      f32x4 m23 = vmax4(vmax4(s[4], s[5]), vmax4(s[6], s[7]));
      f32x4 m4 = vmax4(m01, m23);
      float mx = fmaxf(fmaxf(m4[0], m4[1]), fmaxf(m4[2], m4[3]));
      mx = fmaxf(mx, __shfl_xor(mx, 16));
      mx = fmaxf(mx, __shfl_xor(mx, 32));
      Mn[i] = fmaxf(M[i], mx);
      al[i] = exp2f(M[i] - Mn[i]);
      M[i] = Mn[i];
    }

    // exp + pack + chunked P write, skewed with PV consumption
    f32x4 rs4[2] = {};
#pragma unroll
    for (int ks = 0; ks < 4; ++ks) {
#pragma unroll
      for (int i = 0; i < 2; ++i) {
        f32x4* s = i ? s1 : s0;
        float mn = Mn[i];
#pragma unroll
        for (int jj = 0; jj < 2; ++jj) {
          int j8 = 2 * ks + jj;
          f32x4 arg = s[j8] - mn;
          f32x4 p;
          p[0] = exp2f(arg[0]); p[1] = exp2f(arg[1]);
          p[2] = exp2f(arg[2]); p[3] = exp2f(arg[3]);
          rs4[i] += p;
          half2_t ph0 = pk_cvt(p[0], p[1]);
          half2_t ph1 = pk_cvt(p[2], p[3]);
          half4_t hv;
          hv[0] = ph0[0]; hv[1] = ph0[1]; hv[2] = ph1[0]; hv[3] = ph1[1];
          *(half4_t*)&Pw[(ks & 1) * 1280 + (i * 16 + c) * 40 + jj * 16 + quad * 4] = hv;
        }
      }
      if (ks >= 1) {
        int kk = ks - 1;
        half8 pf0 = *(const half8*)&Pw[(kk & 1) * 1280 + c * 40 + quad * 8];
        half8 pf1 = *(const half8*)&Pw[(kk & 1) * 1280 + (16 + c) * 40 + quad * 8];
#pragma unroll
        for (int n = 0; n < 4; ++n) {
          int d = n * 16 + c;
          int ck = (kk * 4 + quad) ^ (d & 7);
          half8 vf = *(const half8*)&VsT[d * 128 + ck * 8];
          oacc[0][n] = __builtin_amdgcn_mfma_f32_16x16x32_f16(pf0, vf, oacc[0][n], 0, 0, 0);
          oacc[1][n] = __builtin_amdgcn_mfma_f32_16x16x32_f16(pf1, vf, oacc[1][n], 0, 0, 0);
        }
      }
    }
    {
      int kk = 3;
      half8 pf0 = *(const half8*)&Pw[(kk & 1) * 1280 + c * 40 + quad * 8];
      half8 pf1 = *(const half8*)&Pw[(kk & 1) * 1280 + (16 + c) * 40 + quad * 8];
#pragma unroll
      for (int n = 0; n < 4; ++n) {
        int d = n * 16 + c;
        int ck = (kk * 4 + quad) ^ (d & 7);
        half8 vf = *(const half8*)&VsT[d * 128 + ck * 8];
        oacc[0][n] = __builtin_amdgcn_mfma_f32_16x16x32_f16(pf0, vf, oacc[0][n], 0, 0, 0);
        oacc[1][n] = __builtin_amdgcn_mfma_f32_16x16x32_f16(pf1, vf, oacc[1][n], 0, 0, 0);
      }
    }

#pragma unroll
    for (int i = 0; i < 2; ++i) {
      float rs = (rs4[i][0] + rs4[i][1]) + (rs4[i][2] + rs4[i][3]);
      rs += __shfl_xor(rs, 16);
      rs += __shfl_xor(rs, 32);
      L[i] = al[i] * L[i] + rs;  // L IS rescaled; O is NOT (faithful to reference)
    }
  }

  // epilogue: O/L, store f16 to (B,T,1024)
#pragma unroll
  for (int i = 0; i < 2; ++i) {
#pragma unroll
    for (int r = 0; r < 4; ++r) {
      float Lq = __shfl(L[i], quad * 4 + r);
      float inv = 1.0f / Lq;
      int t = qt * 128 + wq0 + i * 16 + quad * 4 + r;
      size_t base = (((size_t)(b * 4096 + t)) << 10) + h * 64;
#pragma unroll
      for (int n = 0; n < 4; ++n)
        Og[base + n * 16 + c] = (_Float16)(oacc[i][n][r] * inv);
    }
  }
}

// ---------------- launcher ----------------
extern "C" void kernel_launch(void* const* d_in, const int* in_sizes, int n_in,
                              void* d_out, int out_size, void* d_ws, size_t ws_size,
                              hipStream_t stream) {
  const float* x = (const float*)d_in[0];
  const float* wq = (const float*)d_in[1];
  const float* bq = (const float*)d_in[2];
  const float* wk = (const float*)d_in[3];
  const float* bk = (const float*)d_in[4];
  const float* wv = (const float*)d_in[5];
  const float* bv = (const float*)d_in[6];
  const float* wo = (const float*)d_in[7];
  const float* bo = (const float*)d_in[8];

  char* ws = (char*)d_ws;
  const size_t MB = 1024 * 1024;
  _Float16* xb = (_Float16*)(ws);               // 32MB; dead after gemm_qkv -> reused as Oatt
  _Float16* wq16 = (_Float16*)(ws + 32 * MB);
  _Float16* wk16 = (_Float16*)(ws + 34 * MB);
  _Float16* wv16 = (_Float16*)(ws + 36 * MB);
  _Float16* wo16 = (_Float16*)(ws + 38 * MB);
  _Float16* Qg = (_Float16*)(ws + 40 * MB);     // (B,H,T,64)
  _Float16* Kg = (_Float16*)(ws + 72 * MB);     // (B,H,T,64)
  _Float16* VgT = (_Float16*)(ws + 104 * MB);   // (B,H,64,T) written directly by gemm_qkv
  _Float16* Oatt = xb;                          // (B,T,1024)

  cvt_f32_f16<<<8192, 256, 0, stream>>>(x, xb, 16777216);
  cvt_w4<<<2048, 256, 0, stream>>>(wq, wk, wv, wo, wq16, wk16, wv16, wo16);

  gemm_qkv<<<dim3(128, 8, 3), 256, 0, stream>>>(xb, wq16, wk16, wv16,
                                                bq, bk, bv, Qg, Kg, VgT);
  fa_kernel<<<dim3(64, 32), 256, 0, stream>>>(Qg, Kg, VgT, Oatt);
  gemm_out<<<dim3(128, 8), 256, 0, stream>>>(Oatt, wo16, bo, (float*)d_out);
}